// Round 11
// baseline (221.412 us; speedup 1.0000x reference)
//
#include <hip/hip_runtime.h>
#include <hip/hip_bf16.h>

namespace {

constexpr int kN = 64, kC = 128, kT = 128, kV = 25, kH = 8, kc = 16;
constexpr int kKS = 13;               // K-steps of 32 (K' = 16c * 26 = 416)
constexpr int kBRow = 36;             // B row pitch in shorts (proven 0-conflict)
constexpr int kBSlab = 224 * kBRow;   // 8064 shorts per (h,cb,k) B slab
constexpr int kXRow = 424;            // A-tile row pitch in shorts (848 B)

typedef __attribute__((ext_vector_type(8))) short bf16x8;
typedef __attribute__((ext_vector_type(8))) unsigned short u16x8;
typedef __attribute__((ext_vector_type(4))) float f32x4;

__device__ inline unsigned short f2bf(float f) {
    unsigned int u = __builtin_bit_cast(unsigned int, f);
    u += 0x7fffu + ((u >> 16) & 1u);   // round-to-nearest-even
    return (unsigned short)(u >> 16);
}
__device__ inline float bf2f(unsigned short s) {
    return __builtin_bit_cast(float, ((unsigned int)s) << 16);
}
__device__ inline void glds16(const void* g, void* l) {
    __builtin_amdgcn_global_load_lds(
        (const __attribute__((address_space(1))) void*)g,
        (__attribute__((address_space(3))) void*)l, 16, 0, 0);
}

// ---------------- P1: w1_i[h][v][w] = fc1/||.|| + pe/||.||  (norm over v) ----
__global__ void precompute_w1(const float* __restrict__ fc1,
                              const float* __restrict__ rpe,
                              const int* __restrict__ hops,
                              float* __restrict__ W1) {
    int ih = blockIdx.x;        // i*8+h, 0..23
    int w = threadIdx.x;
    if (w >= kV) return;
    const float* f = fc1 + ih * kV * kV;
    const float* r = rpe + ih * kV;
    float s1 = 0.f, s2 = 0.f;
    for (int v = 0; v < kV; ++v) {
        float a = f[v * kV + w];
        float p = r[hops[v * kV + w]];
        s1 += a * a; s2 += p * p;
    }
    float n1 = sqrtf(s1) + 1e-4f, n2 = sqrtf(s2) + 1e-4f;
    float* o = W1 + ih * kV * kV;
    for (int v = 0; v < kV; ++v) {
        float a = f[v * kV + w];
        float p = r[hops[v * kV + w]];
        o[v * kV + w] = a / n1 + p / n2;
    }
}

// ---------------- P2: combined weight Wt5[h][cb(2)][k(13)][col(224)][36] -----
// shorts 0..31: kappa = k*32+lo; c=kappa/26, vv=kappa%26 (25 -> 0);
// m = cb*224+col; m<400: d=m/25, w=m%25. shorts 32..35 zero pad.
__global__ void precompute_W(const float* __restrict__ W1,
                             const float* __restrict__ fc2_w,
                             unsigned short* __restrict__ Wt5) {
    int k   = blockIdx.x;   // 0..12
    int hcb = blockIdx.y;   // h*2+cb, 0..15
    int h = hcb >> 1, cb = hcb & 1;
    unsigned short* outp = Wt5 + ((size_t)hcb * kKS + k) * kBSlab;
    for (int e = threadIdx.x; e < kBSlab; e += 256) {
        int col = e / kBRow, lo = e - col * kBRow;
        int m = cb * 224 + col;
        float val = 0.f;
        if (lo < 32 && m < 400) {
            int kap = k * 32 + lo;
            int c = kap / 26, vv = kap - c * 26;
            if (vv < 25) {
                int d = m / 25, w = m - d * 25;
                #pragma unroll
                for (int i = 0; i < 3; ++i) {
                    float wg = fc2_w[(i * kC + h * kc + d) * kc + c];
                    float w1 = W1[((i * kH + h) * kV + vv) * kV + w];
                    val += wg * w1;
                }
            }
        }
        outp[e] = f2bf(val);
    }
}

// ---------------- GEMM: fused convert + mm-loop at 2 blocks/CU ---------------
// block = 32 rows (t-quarter of one n) x 224 cols (cb-half), one h. 4 waves =
// 2 rg x 2 cg; wave = 16 rows x 112 cols: 1 A-frag + 7 B-frags + 7 MFMA /step.
// A converted once into Xl; B glds double-buffered, ONE barrier per K-step.
__global__ __launch_bounds__(256, 2) void gemm_y(const float* __restrict__ x,
                                                 const unsigned short* __restrict__ Wt5,
                                                 unsigned short* __restrict__ yb,
                                                 float2* __restrict__ Pbuf) {
    __shared__ __align__(16) unsigned short Xl[32 * kXRow];   // 27,136 B
    __shared__ __align__(16) unsigned short Bl[2][kBSlab];    // 32,256 B

    const int tq = blockIdx.x, n = blockIdx.y, hcb = blockIdx.z;
    const int h = hcb >> 1, cb = hcb & 1;
    const int t0 = tq * 32;
    const int tid = threadIdx.x, lane = tid & 63, wv = tid >> 6;
    const int rg = wv >> 1, cg = wv & 1;
    const int ll = lane & 15, lh = lane >> 4;

    const float* xbase = x + ((size_t)(n * kC + h * kc) * kT + t0) * kV;  // ch-stride 3200
    const unsigned short* bbase = Wt5 + (size_t)hcb * kKS * kBSlab;

    // ---- prologue: convert x into Xl via bounce (= Bl), 4 rounds of 4 ch ----
    float* bounce = (float*)&Bl[0][0];          // 12,800 B used of 32,256
    for (int s = 0; s < 4; ++s) {
        #pragma unroll
        for (int q = 0; q < 4; ++q) {           // 800 16B chunks
            int e = q * 256 + tid;
            if (e < 800) {
                int c = e / 200, off = e - c * 200;
                glds16(xbase + (size_t)(s * 4 + c) * 3200 + off * 4,
                       (char*)bounce + (size_t)e * 16);
            }
        }
        __syncthreads();                        // slab landed
        if (tid < 128) {                        // thread (c=tid&3, t=tid>>2)
            const int c = tid & 3, t = tid >> 2;
            const float* bp = bounce + c * 800 + t * 25;
            unsigned int* xw = (unsigned int*)&Xl[0] + t * (kXRow / 2);
            const int k0 = (s * 4 + c) * 26;    // kappa base (even)
            #pragma unroll
            for (int p13 = 0; p13 < 13; ++p13) {
                int vv = 2 * p13;
                int kap = k0 + vv;
                int idx = (kap >> 5) * 16 + ((kap & 31) >> 1);
                float f0 = bp[vv];
                float f1 = (vv < 24) ? bp[vv + 1] : 0.f;   // vv=24 pairs w/ pad
                xw[idx] = (unsigned)f2bf(f0) | ((unsigned)f2bf(f1) << 16);
            }
        }
        __syncthreads();                        // bounce free / Xl visible
    }

    // ---- first B stage --------------------------------------------------
    auto stage = [&](int k, int buf) {          // 1008 16B chunks
        const unsigned short* src = bbase + (size_t)k * kBSlab;
        #pragma unroll
        for (int q = 0; q < 4; ++q) {
            int e = q * 256 + tid;
            if (e < 1008) glds16(src + (size_t)e * 8, &Bl[buf][(size_t)e * 8]);
        }
    };
    stage(0, 0);

    f32x4 acc[7];
    #pragma unroll
    for (int i = 0; i < 7; ++i) acc[i] = (f32x4)(0.f);
    __syncthreads();                            // Bl[0] staged

    // ---- main loop: 13 K-steps, dbuf B, ONE barrier per step ---------------
    #pragma unroll 1
    for (int k = 0; k < kKS; ++k) {
        const int cur = k & 1;
        if (k < kKS - 1) stage(k + 1, cur ^ 1);
        bf16x8 af = *(const bf16x8*)&Xl[(size_t)(rg * 16 + ll) * kXRow + k * 32 + lh * 8];
        #pragma unroll
        for (int ci = 0; ci < 7; ++ci) {
            bf16x8 bf = *(const bf16x8*)&Bl[cur][(size_t)((cg * 7 + ci) * 16 + ll) * kBRow + lh * 8];
            acc[ci] = __builtin_amdgcn_mfma_f32_16x16x32_bf16(af, bf, acc[ci], 0, 0, 0);
        }
        __syncthreads();   // Bl[cur] reads done everywhere; stage(k+1) drained
    }

    // ---- epilogue: scattered bf16 y stores (r7: pattern-insensitive) --------
    #pragma unroll
    for (int ci = 0; ci < 7; ++ci) {
        int m = cb * 224 + cg * 112 + ci * 16 + ll;
        if (m < 400) {
            int d = m / 25, w = m - d * 25;
            unsigned short* yp = yb + ((size_t)(n * kC + h * kc + d) * kT
                                       + t0 + rg * 16 + lh * 4) * kV + w;
            #pragma unroll
            for (int r = 0; r < 4; ++r)
                yp[(size_t)r * kV] = f2bf(acc[ci][r]);
        }
    }

    // ---- fused BN partials: per (rg, local col) then per d ------------------
    float2* Bs = (float2*)&Bl[0][0];            // [2][224] float2 = 3,584 B
    #pragma unroll
    for (int ci = 0; ci < 7; ++ci) {
        float s = 0.f, ss = 0.f;
        #pragma unroll
        for (int r = 0; r < 4; ++r) {
            float v = acc[ci][r];
            s += v; ss += v * v;
        }
        s  += __shfl_xor(s, 16);  ss += __shfl_xor(ss, 16);
        s  += __shfl_xor(s, 32);  ss += __shfl_xor(ss, 32);
        if (lh == 0) Bs[rg * 224 + cg * 112 + ci * 16 + ll] = make_float2(s, ss);
    }
    __syncthreads();
    if (tid < 16) {
        int d = tid;
        float s = 0.f, ss = 0.f;
        for (int w = 0; w < 25; ++w) {
            int lc = d * 25 + w - cb * 224;
            if (lc >= 0 && lc < 224) {
                float2 p0 = Bs[lc], p1 = Bs[224 + lc];
                s += p0.x + p1.x; ss += p0.y + p1.y;
            }
        }
        size_t bid = ((size_t)hcb * 64 + n) * 4 + tq;
        Pbuf[bid * 16 + d] = make_float2(s, ss);
    }
}

// ---------------- B2: finalize BN stats (1024 threads, 8-way split) ----------
__global__ void bn_finalize(const float2* __restrict__ Pbuf,
                            const float* __restrict__ gamma,
                            const float* __restrict__ beta,
                            float2* __restrict__ scsh) {
    __shared__ float2 red[1024];
    int tid = threadIdx.x;
    int ch = tid >> 3, g = tid & 7;      // ch 0..127, g 0..7
    int h = ch >> 4, d = ch & 15;
    float s = 0.f, ss = 0.f;
    for (int e = g * 64; e < g * 64 + 64; ++e) {   // e over 512 = cb*256+n*4+tq
        int cb = e >> 8, rem = e & 255;
        int n = rem >> 2, tq = rem & 3;
        float2 p = Pbuf[(((size_t)(h * 2 + cb) * 64 + n) * 4 + tq) * 16 + d];
        s += p.x; ss += p.y;
    }
    red[tid] = make_float2(s, ss);
    __syncthreads();
    if (g == 0) {
        for (int j = 1; j < 8; ++j) {
            float2 p = red[tid + j];
            s += p.x; ss += p.y;
        }
        const float inv = 1.f / (float)(kN * kT * kV);
        float mean = s * inv;
        float var  = ss * inv - mean * mean;
        float sc = gamma[ch] * rsqrtf(var + 1e-5f);
        scsh[ch] = make_float2(sc, beta[ch] - mean * sc);
    }
}

// ---------------- C: out = relu(y*scale + shift + x) -------------------------
__global__ void bn_apply(const unsigned short* __restrict__ yb,
                         const float* __restrict__ x,
                         const float2* __restrict__ scsh,
                         float* __restrict__ out) {
    const size_t total8 = (size_t)kN * kC * kT * kV / 8;   // 3,276,800
    for (size_t i = (size_t)blockIdx.x * blockDim.x + threadIdx.x; i < total8;
         i += (size_t)gridDim.x * blockDim.x) {
        int ch = (int)((i / 400) % kC);          // 400 u16x8 per (n,ch)
        float2 sc = scsh[ch];
        u16x8 yv = ((const u16x8*)yb)[i];
        f32x4 x0 = ((const f32x4*)x)[i * 2];
        f32x4 x1 = ((const f32x4*)x)[i * 2 + 1];
        f32x4 o0, o1;
        #pragma unroll
        for (int q = 0; q < 4; ++q) {
            o0[q] = fmaxf(bf2f((unsigned short)yv[q]) * sc.x + sc.y + x0[q], 0.f);
            o1[q] = fmaxf(bf2f((unsigned short)yv[q + 4]) * sc.x + sc.y + x1[q], 0.f);
        }
        ((f32x4*)out)[i * 2]     = o0;
        ((f32x4*)out)[i * 2 + 1] = o1;
    }
}

} // namespace

extern "C" void kernel_launch(void* const* d_in, const int* in_sizes, int n_in,
                              void* d_out, int out_size, void* d_ws, size_t ws_size,
                              hipStream_t stream) {
    const float* x     = (const float*)d_in[0];
    const float* fc1   = (const float*)d_in[1];
    const float* rpe   = (const float*)d_in[2];
    const int*   hops  = (const int*)d_in[3];
    const float* fc2w  = (const float*)d_in[4];
    // d_in[5] = fc2_b: constant over BN reduction axes -> cancelled by BN.
    const float* gamma = (const float*)d_in[6];
    const float* beta  = (const float*)d_in[7];
    float* out = (float*)d_out;

    char* ws = (char*)d_ws;
    unsigned short* yb   = (unsigned short*)ws;                  // 52,428,800 B
    float*          W1   = (float*)(ws + 52428800);              // 60,000 B (pad 64K)
    unsigned short* Wt5  = (unsigned short*)(ws + 52494336);     // 3,354,624 B
    float2*         Pbuf = (float2*)(ws + 55848960);             // 524,288 B
    float2*         scsh = (float2*)(ws + 56373248);             // 1,024 B

    precompute_w1<<<24, 32, 0, stream>>>(fc1, rpe, hops, W1);
    precompute_W<<<dim3(13, 16), 256, 0, stream>>>(W1, fc2w, Wt5);
    gemm_y<<<dim3(4, 64, 16), 256, 0, stream>>>(x, Wt5, yb, Pbuf);
    bn_finalize<<<1, 1024, 0, stream>>>(Pbuf, gamma, beta, scsh);
    bn_apply<<<2048, 256, 0, stream>>>(yb, x, scsh, out);
}